// Round 6
// baseline (487.926 us; speedup 1.0000x reference)
//
#include <hip/hip_runtime.h>
#include <cstdint>
#include <cstddef>

// Problem constants (fixed by the reference).
#define BN_ 32
#define DD_ 1024
#define TT_ 1000
#define LMAX_ 200
#define VC_ 80
#define BLANK_ 79
#define SS_ 401          // 2*LMAX+1
#define SPAD 512         // padded S: 64 lanes x 8 states
#define EMW 256          // compact emit row: 200 labels + 55 zeros + blank@255
#define NEGV (-1e30f)

typedef _Float16 half8 __attribute__((ext_vector_type(8)));
typedef float f32x4 __attribute__((ext_vector_type(4)));

// Async global->LDS, 16B per lane. LDS dest is wave-uniform base + lane*16.
__device__ __forceinline__ void async16(const void* g, void* l) {
  __builtin_amdgcn_global_load_lds(
      (const __attribute__((address_space(1))) unsigned int*)g,
      (__attribute__((address_space(3))) unsigned int*)l, 16, 0, 0);
}

// ---------------------------------------------------------------------------
// Fused transpose+cast for all three inputs, one launch.
// z<32: dec slice z [1024,1000] -> Af[z] [1000,1024]
// z=32: W1 [1024,1024] -> W1T;  z=33: W2 [1024,80] -> W2T.  (R=1024 always)
// 64x64 tiles; loads 64-lane coalesced f32; stores 128B-contiguous f16 rows.
// ---------------------------------------------------------------------------
__global__ __launch_bounds__(256) void transpose_all_kernel(
    const float* __restrict__ dec, const float* __restrict__ W1,
    const float* __restrict__ W2, _Float16* __restrict__ Af,
    _Float16* __restrict__ W1T, _Float16* __restrict__ W2T) {
  __shared__ _Float16 T[64][72];  // [c][r], pad 72 keeps rows 16B-aligned
  int z = blockIdx.z;
  const float* in; _Float16* out; int C;
  const int R = 1024;
  if (z < 32) {
    in = dec + (size_t)z * R * TT_;
    out = Af + (size_t)z * TT_ * R;
    C = TT_;
  } else if (z == 32) {
    in = W1; out = W1T; C = 1024;
  } else {
    in = W2; out = W2T; C = VC_;
  }
  int c0 = blockIdx.x * 64, r0 = blockIdx.y * 64;
  if (c0 >= C) return;
  int tid = threadIdx.x;
  // Load: c = c0 + (tid&63); rows r0 + (tid>>6)*16 + i  (i=0..15)
  int cl = tid & 63, rg = tid >> 6;
  int c = c0 + cl;
  bool cv = (c < C);
  const float* ip = in + (size_t)(r0 + rg * 16) * C + c;
  _Float16 h[16];
#pragma unroll
  for (int i = 0; i < 16; ++i) h[i] = cv ? (_Float16)ip[(size_t)i * C] : (_Float16)0.f;
  *(half8*)&T[cl][rg * 16] = *(half8*)&h[0];
  *(half8*)&T[cl][rg * 16 + 8] = *(half8*)&h[8];
  __syncthreads();
  // Store: c_row = tid>>2, r-chunk = (tid&3)*16 -> 32B per thread, rows of
  // 128B formed by 4 consecutive threads.
  int cr = tid >> 2, rc = (tid & 3) * 16;
  if (c0 + cr < C) {
    half8 a = *(const half8*)&T[cr][rc];
    half8 b2 = *(const half8*)&T[cr][rc + 8];
    _Float16* op = out + (size_t)(c0 + cr) * R + r0 + rc;
    *(half8*)op = a;
    *(half8*)(op + 8) = b2;
  }
}

// ---------------------------------------------------------------------------
// GEMM1: H = relu(A[M,K] @ W1[K,N] + b1).
// 256x256 tile, BK=64, 8 waves, 4-phase pipelined schedule.
// R5 (proven 80.2us, MfmaUtil 36%): R1's staging cadence + vmcnt distance
// with fragment reuse (24 ds_read_b128/K-tile/wave).
// R2/R4 lesson: regressions came from SHORTENED PREFETCH DISTANCE, not
// read count. Single vmcnt(6)@q3 waits on loads issued >=4 phases earlier.
// ---------------------------------------------------------------------------
__device__ __forceinline__ void stage_half(const _Float16* __restrict__ X,
                                           int x0, int kt, int h,
                                           _Float16* lds, int tid, int K) {
#pragma unroll
  for (int jj = 0; jj < 2; ++jj) {
    int seg = tid + 512 * jj;          // 1024 16B segments per half-tile
    int row = seg >> 3, slot = seg & 7;
    int cg = slot ^ (row & 7);         // pre-swizzled global chunk
    async16(X + (size_t)(x0 + h * 128 + row) * K + kt * 64 + cg * 8,
            lds + seg * 8);
  }
}

__global__ __launch_bounds__(512, 2) void gemm_relu_kernel(
    const _Float16* __restrict__ A, const _Float16* __restrict__ Bt,
    const float* __restrict__ bias, _Float16* __restrict__ H,
    int M, int N, int K) {
  __shared__ __align__(16) _Float16 sA[2][16384];  // 2 x 32 KB
  __shared__ __align__(16) _Float16 sB[2][16384];  // 2 x 32 KB  (total 128 KB)
  int tid = threadIdx.x;
  int wave = tid >> 6, lane = tid & 63;
  int quad = lane >> 4, r16 = lane & 15;
  int wm = wave >> 2, wn = wave & 3;  // 2 (M) x 4 (N) waves per quadrant

  // Bijective XCD swizzle (nwg % 8 != 0 -> m204 variant), then 4 consecutive
  // wg share one A row-panel (ntile fastest) for L2 locality.
  int orig = blockIdx.x, nwg = gridDim.x;
  int xcd = orig & 7, loc = orig >> 3;
  int qq = nwg >> 3, rr = nwg & 7;
  int wg = (xcd < rr ? xcd * (qq + 1) : rr * (qq + 1) + (xcd - rr) * qq) + loc;
  int m0 = (wg >> 2) * 256, n0 = (wg & 3) * 256;

  f32x4 acc[4][8];
#pragma unroll
  for (int q = 0; q < 4; ++q)
#pragma unroll
    for (int f = 0; f < 8; ++f) acc[q][f] = {0.f, 0.f, 0.f, 0.f};

  // Prologue: tile0 fully (4 halves), then tile1's A-h0, B-h0, A-h1.
  stage_half(A, m0, 0, 0, &sA[0][0], tid, K);
  stage_half(A, m0, 0, 1, &sA[0][8192], tid, K);
  stage_half(Bt, n0, 0, 0, &sB[0][0], tid, K);
  stage_half(Bt, n0, 0, 1, &sB[0][8192], tid, K);
  stage_half(A, m0, 1, 0, &sA[1][0], tid, K);
  stage_half(Bt, n0, 1, 0, &sB[1][0], tid, K);
  stage_half(A, m0, 1, 1, &sA[1][8192], tid, K);
  asm volatile("s_waitcnt vmcnt(6)" ::: "memory");  // tile0 landed, 6 in flight
  __builtin_amdgcn_s_barrier();

  const int NKT = K >> 6;  // 16
#pragma unroll 2
  for (int t = 0; t < NKT; ++t) {
    int cur = t & 1, nxt = cur ^ 1;
    int t1 = (t + 1 < NKT) ? t + 1 : NKT - 1;  // clamped (keeps vmcnt uniform)
    int t2 = (t + 2 < NKT) ? t + 2 : NKT - 1;
    const _Float16* As = sA[cur];
    const _Float16* Bs = sB[cur];
    int sw0 = ((0 * 4 + quad) ^ (r16 & 7)) * 8;
    int sw1 = ((1 * 4 + quad) ^ (r16 & 7)) * 8;
    half8 af[4][2];      // loaded at qn==0 phases, reused at qn==1
    half8 bfr[2][2][2];  // [qn][j][ku]: bf0 @ q0, bf1 @ q1, reused @ q2,q3
#pragma unroll
    for (int q = 0; q < 4; ++q) {
      const int qm = q >> 1, qn = q & 1;
      if (qn == 0) {
        int abase = (qm * 128 + wm * 64 + r16) * 64;
#pragma unroll
        for (int i = 0; i < 4; ++i) {
          af[i][0] = *(const half8*)&As[abase + i * 16 * 64 + sw0];
          af[i][1] = *(const half8*)&As[abase + i * 16 * 64 + sw1];
        }
      }
      if (qm == 0) {
        int bbase = (qn * 128 + wn * 32 + r16) * 64;
#pragma unroll
        for (int j = 0; j < 2; ++j) {
          bfr[qn][j][0] = *(const half8*)&Bs[bbase + j * 16 * 64 + sw0];
          bfr[qn][j][1] = *(const half8*)&Bs[bbase + j * 16 * 64 + sw1];
        }
      }
      // Stage one half-tile (issued after this phase's ds-reads). R1-exact.
      if (q == 0) stage_half(Bt, n0, t1, 1, &sB[nxt][8192], tid, K);
      else if (q == 1) stage_half(A, m0, t2, 0, &sA[cur][0], tid, K);
      else if (q == 2) stage_half(Bt, n0, t2, 0, &sB[cur][0], tid, K);
      else stage_half(A, m0, t2, 1, &sA[cur][8192], tid, K);
      __builtin_amdgcn_s_barrier();
      asm volatile("s_waitcnt lgkmcnt(0)" ::: "memory");
      __builtin_amdgcn_s_setprio(1);
#pragma unroll
      for (int i = 0; i < 4; ++i)
#pragma unroll
        for (int j = 0; j < 2; ++j) {
          acc[q][i * 2 + j] = __builtin_amdgcn_mfma_f32_16x16x32_f16(
              af[i][0], bfr[qn][j][0], acc[q][i * 2 + j], 0, 0, 0);
          acc[q][i * 2 + j] = __builtin_amdgcn_mfma_f32_16x16x32_f16(
              af[i][1], bfr[qn][j][1], acc[q][i * 2 + j], 0, 0, 0);
        }
      __builtin_amdgcn_s_setprio(0);
      if (q == 3) asm volatile("s_waitcnt vmcnt(6)" ::: "memory");
      __builtin_amdgcn_s_barrier();
    }
  }
  asm volatile("s_waitcnt vmcnt(0)" ::: "memory");  // drain clamped prefetch

  // Epilogue: bias + ReLU, f16 store.
  float bvv[2][2];
#pragma unroll
  for (int qn = 0; qn < 2; ++qn)
#pragma unroll
    for (int j = 0; j < 2; ++j)
      bvv[qn][j] = bias[n0 + qn * 128 + wn * 32 + j * 16 + r16];
#pragma unroll
  for (int q = 0; q < 4; ++q) {
    const int qm = q >> 1, qn = q & 1;
#pragma unroll
    for (int i = 0; i < 4; ++i)
#pragma unroll
      for (int j = 0; j < 2; ++j) {
#pragma unroll
        for (int r = 0; r < 4; ++r) {
          int m = m0 + qm * 128 + wm * 64 + i * 16 + quad * 4 + r;
          int n = n0 + qn * 128 + wn * 32 + j * 16 + r16;
          float v = acc[q][i * 2 + j][r] + bvv[qn][j];
          H[(size_t)m * N + n] = (_Float16)fmaxf(v, 0.f);
        }
      }
  }
}

// ---------------------------------------------------------------------------
// GEMM2 + fused SOFTMAX + fused COMPACT EMIT (R6): probs for a 64-row tile
// staged in LDS, then writes EMC[m][0..255]: slots 0..199 = P[tg[l]],
// 200..254 = 0, 255 = blank.  Row = 1KB (was 2KB) -> halves EM write here
// and EM read in ctc_dp.  Emission VALUES identical -> bitwise-same result.
// ---------------------------------------------------------------------------
__global__ __launch_bounds__(256) void gemm_prob_kernel(
    const _Float16* __restrict__ A, const _Float16* __restrict__ Bt,
    const float* __restrict__ bias, const int* __restrict__ targets,
    float* __restrict__ EM, int M, int K) {
  constexpr int BK = 64;
  __shared__ __align__(16) _Float16 sA[64 * BK];   // 8 KB
  __shared__ __align__(16) _Float16 sB[VC_ * BK];  // 10 KB
  __shared__ float sP[64][VC_];                    // 20 KB prob tile
  int tid = threadIdx.x;
  int wave = tid >> 6, lane = tid & 63;
  int quad = lane >> 4, r16 = lane & 15;
  int m0 = blockIdx.x * 64;

  f32x4 acc[5];
#pragma unroll
  for (int j = 0; j < 5; ++j) acc[j] = {0.f, 0.f, 0.f, 0.f};

  for (int kt = 0; kt < K; kt += BK) {
#pragma unroll
    for (int jj = 0; jj < 2; ++jj) {
      int seg = tid + 256 * jj;  // 512 segs
      int row = seg >> 3, slot = seg & 7;
      int cg = slot ^ (row & 7);
      async16(A + (size_t)(m0 + row) * K + kt + cg * 8, &sA[seg * 8]);
    }
#pragma unroll
    for (int jj = 0; jj < 3; ++jj) {
      int seg = tid + 256 * jj;
      if (seg < VC_ * 8) {  // 640 segs; whole-wave masking
        int row = seg >> 3, slot = seg & 7;
        int cg = slot ^ (row & 7);
        async16(Bt + (size_t)row * K + kt + cg * 8, &sB[seg * 8]);
      }
    }
    __syncthreads();
#pragma unroll
    for (int ku = 0; ku < 2; ++ku) {
      int sw = ((ku * 4 + quad) ^ (r16 & 7)) * 8;
      half8 af = *(const half8*)&sA[(wave * 16 + r16) * BK + sw];
      half8 bfr[5];
#pragma unroll
      for (int j = 0; j < 5; ++j)
        bfr[j] = *(const half8*)&sB[(j * 16 + r16) * BK + sw];
#pragma unroll
      for (int j = 0; j < 5; ++j)
        acc[j] = __builtin_amdgcn_mfma_f32_16x16x32_f16(af, bfr[j], acc[j], 0, 0, 0);
    }
    __syncthreads();
  }
  float bv[5];
#pragma unroll
  for (int j = 0; j < 5; ++j) bv[j] = bias[j * 16 + r16];
#pragma unroll
  for (int rr = 0; rr < 4; ++rr) {
    float vals[5];
    float mx = -3.4e38f;
#pragma unroll
    for (int j = 0; j < 5; ++j) {
      vals[j] = acc[j][rr] + bv[j];
      mx = fmaxf(mx, vals[j]);
    }
#pragma unroll
    for (int d = 1; d < 16; d <<= 1) mx = fmaxf(mx, __shfl_xor(mx, d));
    float ex[5], sm = 0.f;
#pragma unroll
    for (int j = 0; j < 5; ++j) { ex[j] = __expf(vals[j] - mx); sm += ex[j]; }
#pragma unroll
    for (int d = 1; d < 16; d <<= 1) sm += __shfl_xor(sm, d);
    float rinv = 1.f / sm;
    int ml = wave * 16 + quad * 4 + rr;
#pragma unroll
    for (int j = 0; j < 5; ++j) sP[ml][j * 16 + r16] = ex[j] * rinv;
  }
  __syncthreads();

  // Compact emit: 64 rows x 256 slots; 4 threads per row, 64 slots each
  // (contiguous 256 B float4 stores).
  {
    int row = tid >> 2, q4 = tid & 3;
    int m = m0 + row;
    int b = m / TT_;
    const int* tg = targets + b * LMAX_;
    const float* pr = sP[row];
    float pb = pr[BLANK_];
    float* o = EM + (size_t)m * EMW + q4 * 64;
#pragma unroll 4
    for (int sc = 0; sc < 64; sc += 4) {
      int l = q4 * 64 + sc;
      float4 vv;
      vv.x = (l + 0 < LMAX_) ? pr[tg[l + 0]] : 0.f;
      vv.y = (l + 1 < LMAX_) ? pr[tg[l + 1]] : 0.f;
      vv.z = (l + 2 < LMAX_) ? pr[tg[l + 2]] : 0.f;
      vv.w = (l + 3 < LMAX_) ? pr[tg[l + 3]] : ((l + 3 == 255) ? pb : 0.f);
      *(float4*)o = vv;
      o += 4;
    }
  }
}

// ---------------------------------------------------------------------------
// CTC DP, forward/backward split. Linear domain, PER-LANE block-float scale.
// R6: reads compact EMC rows — one f32x4/lane (labels 4L..4L+3) + uniform
// blank load; e0={bl,lv.x,bl,lv.y}, e1={bl,lv.z,bl,lv.w} reproduces the old
// per-state emissions exactly for s<=2*LMAX.  States s>2*Ll now see blank
// (not 0) emissions: harmless — beta==0 above s2 (backward recurrence pulls
// only from higher, zero states), so contaminated alpha x beta terms vanish;
// per-lane k unaffected across lanes.
// ---------------------------------------------------------------------------
__device__ __forceinline__ void dp_step_fwd(float (&bta)[8], int& k,
                                            const f32x4 e0, const f32x4 e1,
                                            const float (&am)[4], int lane) {
  float pm1 = __shfl_up(bta[7], 1);   // alpha[s0-1] (prev lane r=7)
  int pk = __shfl_up(k, 1);
  if (lane == 0) { pm1 = 0.f; pk = k; }
  int knew = max(k, pk);
  pm1 = ldexpf(pm1, pk - knew);
  int ds = k - knew;
#pragma unroll
  for (int r = 0; r < 8; ++r) bta[r] = ldexpf(bta[r], ds);
  k = knew;
  float nb[8];
  nb[0] = (bta[0] + pm1) * e0.x;
  nb[1] = fmaf(am[0], pm1, bta[1] + bta[0]) * e0.y;
  nb[2] = (bta[2] + bta[1]) * e0.z;
  nb[3] = fmaf(am[1], bta[1], bta[3] + bta[2]) * e0.w;
  nb[4] = (bta[4] + bta[3]) * e1.x;
  nb[5] = fmaf(am[2], bta[3], bta[5] + bta[4]) * e1.y;
  nb[6] = (bta[6] + bta[5]) * e1.z;
  nb[7] = fmaf(am[3], bta[5], bta[7] + bta[6]) * e1.w;
#pragma unroll
  for (int r = 0; r < 8; ++r) bta[r] = nb[r];
}

__device__ __forceinline__ void dp_step_bwd(float (&g)[8], int& k,
                                            const f32x4 e0, const f32x4 e1,
                                            const float (&amB)[4], int lane) {
  float gh[8];
  gh[0] = g[0] * e0.x; gh[1] = g[1] * e0.y;
  gh[2] = g[2] * e0.z; gh[3] = g[3] * e0.w;
  gh[4] = g[4] * e1.x; gh[5] = g[5] * e1.y;
  gh[6] = g[6] * e1.z; gh[7] = g[7] * e1.w;
  float qm1 = __shfl_down(gh[0], 1);
  float qm2 = __shfl_down(gh[1], 1);
  int nk = __shfl_down(k, 1);
  if (lane == 63) { qm1 = 0.f; qm2 = 0.f; nk = k; }
  int knew = max(k, nk);
  int dq = nk - knew;
  qm1 = ldexpf(qm1, dq);
  qm2 = ldexpf(qm2, dq);
  int ds = k - knew;
#pragma unroll
  for (int r = 0; r < 8; ++r) gh[r] = ldexpf(gh[r], ds);
  k = knew;
  g[0] = gh[0] + gh[1];
  g[1] = fmaf(amB[0], gh[3], gh[1] + gh[2]);
  g[2] = gh[2] + gh[3];
  g[3] = fmaf(amB[1], gh[5], gh[3] + gh[4]);
  g[4] = gh[4] + gh[5];
  g[5] = fmaf(amB[2], gh[7], gh[5] + gh[6]);
  g[6] = gh[6] + gh[7];
  g[7] = fmaf(amB[3], qm2, gh[7] + qm1);
}

__device__ __forceinline__ void dp_rescale(float (&v)[8], int& k) {
  float m = fmaxf(fmaxf(fmaxf(v[0], v[1]), fmaxf(v[2], v[3])),
                  fmaxf(fmaxf(v[4], v[5]), fmaxf(v[6], v[7])));
  int ex = (__float_as_int(m) >> 23) - 126;  // m>=0; m==0 -> harmless drift
  k += ex;
#pragma unroll
  for (int r = 0; r < 8; ++r) v[r] = ldexpf(v[r], -ex);
}

__device__ __forceinline__ float allow_f(const int* __restrict__ tg, int s) {
  if (!(s & 1) || s < 3) return 0.f;
  int li = s >> 1;
  if (li >= LMAX_) return 0.f;
  int lab = tg[li];
  return (lab != BLANK_ && lab != tg[li - 1]) ? 1.f : 0.f;
}

__global__ __launch_bounds__(128) void ctc_dp_kernel(
    const float* __restrict__ EM, const int* __restrict__ targets,
    const int* __restrict__ dlen, const int* __restrict__ tlen,
    float* __restrict__ out) {
  __shared__ float sg[SPAD];
  __shared__ int skg[64];
  int b = blockIdx.x;
  int wave = threadIdx.x >> 6;
  int lane = threadIdx.x & 63;
  const float* em4 = EM + (size_t)b * TT_ * EMW + lane * 4;   // labels 4L..4L+3
  const float* embl = EM + (size_t)b * TT_ * EMW + 255;       // blank (uniform)
  const int* tg = targets + b * LMAX_;
  int Tl = dlen[b], Ll = tlen[b];
  int tm = Tl >> 1;

  constexpr int PD = 8;
  f32x4 pf[PD];
  float pb[PD];
  float v[8];
  int k = 0;

  if (wave == 0) {
    float am[4];
#pragma unroll
    for (int j = 0; j < 4; ++j) am[j] = allow_f(tg, lane * 8 + 2 * j + 1);
    f32x4 lv0 = *(const f32x4*)(em4);
    float bl0 = embl[0];
#pragma unroll
    for (int r = 0; r < 8; ++r) v[r] = 0.f;
    if (lane == 0) { v[0] = bl0; v[1] = lv0.x; }
#pragma unroll
    for (int j = 0; j < PD; ++j) {
      int ri = min(1 + j, TT_ - 1);
      pf[j] = *(const f32x4*)(em4 + (size_t)ri * EMW);
      pb[j] = embl[(size_t)ri * EMW];
    }
    int t = 1;
    for (; t + (PD - 1) <= tm; t += PD) {
#pragma unroll
      for (int u = 0; u < PD; ++u) {
        f32x4 lv = pf[u]; float bl = pb[u];
        f32x4 e0 = {bl, lv.x, bl, lv.y};
        f32x4 e1 = {bl, lv.z, bl, lv.w};
        dp_step_fwd(v, k, e0, e1, am, lane);
        if (u & 1) dp_rescale(v, k);
        int ri = min(t + u + PD, TT_ - 1);
        pf[u] = *(const f32x4*)(em4 + (size_t)ri * EMW);
        pb[u] = embl[(size_t)ri * EMW];
      }
    }
#pragma unroll
    for (int u = 0; u < PD; ++u) {
      if (t + u <= tm) {
        f32x4 lv = pf[u]; float bl = pb[u];
        f32x4 e0 = {bl, lv.x, bl, lv.y};
        f32x4 e1 = {bl, lv.z, bl, lv.w};
        dp_step_fwd(v, k, e0, e1, am, lane);
        if (u & 1) dp_rescale(v, k);
      }
    }
  } else {
    float amB[4];
#pragma unroll
    for (int j = 0; j < 4; ++j) amB[j] = allow_f(tg, lane * 8 + 2 * j + 3);
    int s1 = 2 * Ll - 1, s2 = 2 * Ll;
#pragma unroll
    for (int r = 0; r < 8; ++r) {
      int s = lane * 8 + r;
      v[r] = (s == s1 || s == s2) ? 1.f : 0.f;
    }
#pragma unroll
    for (int j = 0; j < PD; ++j) {
      int ri = max(Tl - 1 - j, 0);
      pf[j] = *(const f32x4*)(em4 + (size_t)ri * EMW);
      pb[j] = embl[(size_t)ri * EMW];
    }
    int t = Tl - 1;
    for (; t - (PD - 1) > tm; t -= PD) {
#pragma unroll
      for (int u = 0; u < PD; ++u) {
        f32x4 lv = pf[u]; float bl = pb[u];
        f32x4 e0 = {bl, lv.x, bl, lv.y};
        f32x4 e1 = {bl, lv.z, bl, lv.w};
        dp_step_bwd(v, k, e0, e1, amB, lane);
        if (u & 1) dp_rescale(v, k);
        int ri = max(t - u - PD, 0);
        pf[u] = *(const f32x4*)(em4 + (size_t)ri * EMW);
        pb[u] = embl[(size_t)ri * EMW];
      }
    }
#pragma unroll
    for (int u = 0; u < PD; ++u) {
      if (t - u > tm) {
        f32x4 lv = pf[u]; float bl = pb[u];
        f32x4 e0 = {bl, lv.x, bl, lv.y};
        f32x4 e1 = {bl, lv.z, bl, lv.w};
        dp_step_bwd(v, k, e0, e1, amB, lane);
        if (u & 1) dp_rescale(v, k);
      }
    }
#pragma unroll
    for (int r = 0; r < 8; ++r) sg[lane * 8 + r] = v[r];
    skg[lane] = k;
  }
  __syncthreads();
  if (wave == 0) {
    float p = 0.f;
#pragma unroll
    for (int r = 0; r < 8; ++r) p = fmaf(v[r], sg[lane * 8 + r], p);
    int kk = k + skg[lane];
    if (p == 0.f) kk = -(1 << 30);
#pragma unroll
    for (int d = 1; d < 64; d <<= 1) {
      float po = __shfl_xor(p, d);
      int ko = __shfl_xor(kk, d);
      int km = max(kk, ko);
      p = ldexpf(p, kk - km) + ldexpf(po, ko - km);
      kk = km;
    }
    if (lane == 0) {
      float nll = 0.f;
      if (p > 0.f) nll = -((log2f(p) + (float)kk) * 0.69314718055994531f);
      atomicAdd(out, nll / (float)Tl * (1.f / BN_));
    }
  }
}

// ---------------------------------------------------------------------------
extern "C" void kernel_launch(void* const* d_in, const int* in_sizes, int n_in,
                              void* d_out, int out_size, void* d_ws, size_t ws_size,
                              hipStream_t stream) {
  const float* dec = (const float*)d_in[0];   // [B, D, T] f32
  const int* tgt   = (const int*)d_in[1];     // [B, LMAX]
  const int* dln   = (const int*)d_in[2];     // [B]
  const int* tln   = (const int*)d_in[3];     // [B]
  const float* W1  = (const float*)d_in[4];   // [D, D]
  const float* b1  = (const float*)d_in[5];   // [D]
  const float* W2  = (const float*)d_in[6];   // [D, V]
  const float* b2  = (const float*)d_in[7];   // [V]
  float* out = (float*)d_out;

  char* ws = (char*)d_ws;
  const size_t M = (size_t)BN_ * TT_;  // 32000
  _Float16* Af   = (_Float16*)(ws);                 // [M, D] f16
  float* EM      = (float*)(ws);                    // [B,T,EMW] f32 (aliases Af)
  _Float16* Hf   = (_Float16*)(ws + 65536000);      // [M, D] f16
  _Float16* W1T  = (_Float16*)(ws + 131072000);     // [D, D] f16 (W1^T)
  _Float16* W2T  = (_Float16*)(ws + 133169152);     // [V, D] f16 (W2^T)

  hipMemsetAsync(d_out, 0, sizeof(float), stream);

  transpose_all_kernel<<<dim3(16, 16, 34), 256, 0, stream>>>(
      dec, W1, W2, Af, W1T, W2T);
  gemm_relu_kernel<<<dim3((1024 / 256) * (M / 256), 1, 1), 512, 0, stream>>>(
      Af, W1T, b1, Hf, (int)M, DD_, DD_);
  gemm_prob_kernel<<<dim3(M / 64, 1, 1), 256, 0, stream>>>(
      Hf, W2T, b2, tgt, EM, (int)M, DD_);
  ctc_dp_kernel<<<dim3(BN_, 1, 1), 128, 0, stream>>>(EM, tgt, dln, tln, out);
}

// Round 7
// 395.809 us; speedup vs baseline: 1.2327x; 1.2327x over previous
//
#include <hip/hip_runtime.h>
#include <cstdint>
#include <cstddef>

// Problem constants (fixed by the reference).
#define BN_ 32
#define DD_ 1024
#define TT_ 1000
#define LMAX_ 200
#define VC_ 80
#define BLANK_ 79
#define SS_ 401          // 2*LMAX+1
#define SPAD 512         // padded S: 64 lanes x 8 states
#define EMW 320          // compact emit row: 200 labels + 56 zeros + 64 blank copies
#define NEGV (-1e30f)

typedef _Float16 half8 __attribute__((ext_vector_type(8)));
typedef float f32x4 __attribute__((ext_vector_type(4)));

// Async global->LDS, 16B per lane. LDS dest is wave-uniform base + lane*16.
__device__ __forceinline__ void async16(const void* g, void* l) {
  __builtin_amdgcn_global_load_lds(
      (const __attribute__((address_space(1))) unsigned int*)g,
      (__attribute__((address_space(3))) unsigned int*)l, 16, 0, 0);
}

// ---------------------------------------------------------------------------
// Fused transpose+cast for all three inputs, one launch.
// z<32: dec slice z [1024,1000] -> Af[z] [1000,1024]
// z=32: W1 [1024,1024] -> W1T;  z=33: W2 [1024,80] -> W2T.  (R=1024 always)
// 64x64 tiles; loads 64-lane coalesced f32; stores 128B-contiguous f16 rows.
// ---------------------------------------------------------------------------
__global__ __launch_bounds__(256) void transpose_all_kernel(
    const float* __restrict__ dec, const float* __restrict__ W1,
    const float* __restrict__ W2, _Float16* __restrict__ Af,
    _Float16* __restrict__ W1T, _Float16* __restrict__ W2T) {
  __shared__ _Float16 T[64][72];  // [c][r], pad 72 keeps rows 16B-aligned
  int z = blockIdx.z;
  const float* in; _Float16* out; int C;
  const int R = 1024;
  if (z < 32) {
    in = dec + (size_t)z * R * TT_;
    out = Af + (size_t)z * TT_ * R;
    C = TT_;
  } else if (z == 32) {
    in = W1; out = W1T; C = 1024;
  } else {
    in = W2; out = W2T; C = VC_;
  }
  int c0 = blockIdx.x * 64, r0 = blockIdx.y * 64;
  if (c0 >= C) return;
  int tid = threadIdx.x;
  // Load: c = c0 + (tid&63); rows r0 + (tid>>6)*16 + i  (i=0..15)
  int cl = tid & 63, rg = tid >> 6;
  int c = c0 + cl;
  bool cv = (c < C);
  const float* ip = in + (size_t)(r0 + rg * 16) * C + c;
  _Float16 h[16];
#pragma unroll
  for (int i = 0; i < 16; ++i) h[i] = cv ? (_Float16)ip[(size_t)i * C] : (_Float16)0.f;
  *(half8*)&T[cl][rg * 16] = *(half8*)&h[0];
  *(half8*)&T[cl][rg * 16 + 8] = *(half8*)&h[8];
  __syncthreads();
  // Store: c_row = tid>>2, r-chunk = (tid&3)*16 -> 32B per thread, rows of
  // 128B formed by 4 consecutive threads.
  int cr = tid >> 2, rc = (tid & 3) * 16;
  if (c0 + cr < C) {
    half8 a = *(const half8*)&T[cr][rc];
    half8 b2 = *(const half8*)&T[cr][rc + 8];
    _Float16* op = out + (size_t)(c0 + cr) * R + r0 + rc;
    *(half8*)op = a;
    *(half8*)(op + 8) = b2;
  }
}

// ---------------------------------------------------------------------------
// GEMM1: H = relu(A[M,K] @ W1[K,N] + b1).
// 256x256 tile, BK=64, 8 waves, 4-phase pipelined schedule.
// R5 (proven 80.2us, MfmaUtil 36%): R1's staging cadence + vmcnt distance
// with fragment reuse (24 ds_read_b128/K-tile/wave).
// R2/R4 lesson: regressions came from SHORTENED PREFETCH DISTANCE, not
// read count. Single vmcnt(6)@q3 waits on loads issued >=4 phases earlier.
// ---------------------------------------------------------------------------
__device__ __forceinline__ void stage_half(const _Float16* __restrict__ X,
                                           int x0, int kt, int h,
                                           _Float16* lds, int tid, int K) {
#pragma unroll
  for (int jj = 0; jj < 2; ++jj) {
    int seg = tid + 512 * jj;          // 1024 16B segments per half-tile
    int row = seg >> 3, slot = seg & 7;
    int cg = slot ^ (row & 7);         // pre-swizzled global chunk
    async16(X + (size_t)(x0 + h * 128 + row) * K + kt * 64 + cg * 8,
            lds + seg * 8);
  }
}

__global__ __launch_bounds__(512, 2) void gemm_relu_kernel(
    const _Float16* __restrict__ A, const _Float16* __restrict__ Bt,
    const float* __restrict__ bias, _Float16* __restrict__ H,
    int M, int N, int K) {
  __shared__ __align__(16) _Float16 sA[2][16384];  // 2 x 32 KB
  __shared__ __align__(16) _Float16 sB[2][16384];  // 2 x 32 KB  (total 128 KB)
  int tid = threadIdx.x;
  int wave = tid >> 6, lane = tid & 63;
  int quad = lane >> 4, r16 = lane & 15;
  int wm = wave >> 2, wn = wave & 3;  // 2 (M) x 4 (N) waves per quadrant

  // Bijective XCD swizzle (nwg % 8 != 0 -> m204 variant), then 4 consecutive
  // wg share one A row-panel (ntile fastest) for L2 locality.
  int orig = blockIdx.x, nwg = gridDim.x;
  int xcd = orig & 7, loc = orig >> 3;
  int qq = nwg >> 3, rr = nwg & 7;
  int wg = (xcd < rr ? xcd * (qq + 1) : rr * (qq + 1) + (xcd - rr) * qq) + loc;
  int m0 = (wg >> 2) * 256, n0 = (wg & 3) * 256;

  f32x4 acc[4][8];
#pragma unroll
  for (int q = 0; q < 4; ++q)
#pragma unroll
    for (int f = 0; f < 8; ++f) acc[q][f] = {0.f, 0.f, 0.f, 0.f};

  // Prologue: tile0 fully (4 halves), then tile1's A-h0, B-h0, A-h1.
  stage_half(A, m0, 0, 0, &sA[0][0], tid, K);
  stage_half(A, m0, 0, 1, &sA[0][8192], tid, K);
  stage_half(Bt, n0, 0, 0, &sB[0][0], tid, K);
  stage_half(Bt, n0, 0, 1, &sB[0][8192], tid, K);
  stage_half(A, m0, 1, 0, &sA[1][0], tid, K);
  stage_half(Bt, n0, 1, 0, &sB[1][0], tid, K);
  stage_half(A, m0, 1, 1, &sA[1][8192], tid, K);
  asm volatile("s_waitcnt vmcnt(6)" ::: "memory");  // tile0 landed, 6 in flight
  __builtin_amdgcn_s_barrier();

  const int NKT = K >> 6;  // 16
#pragma unroll 2
  for (int t = 0; t < NKT; ++t) {
    int cur = t & 1, nxt = cur ^ 1;
    int t1 = (t + 1 < NKT) ? t + 1 : NKT - 1;  // clamped (keeps vmcnt uniform)
    int t2 = (t + 2 < NKT) ? t + 2 : NKT - 1;
    const _Float16* As = sA[cur];
    const _Float16* Bs = sB[cur];
    int sw0 = ((0 * 4 + quad) ^ (r16 & 7)) * 8;
    int sw1 = ((1 * 4 + quad) ^ (r16 & 7)) * 8;
    half8 af[4][2];      // loaded at qn==0 phases, reused at qn==1
    half8 bfr[2][2][2];  // [qn][j][ku]: bf0 @ q0, bf1 @ q1, reused @ q2,q3
#pragma unroll
    for (int q = 0; q < 4; ++q) {
      const int qm = q >> 1, qn = q & 1;
      if (qn == 0) {
        int abase = (qm * 128 + wm * 64 + r16) * 64;
#pragma unroll
        for (int i = 0; i < 4; ++i) {
          af[i][0] = *(const half8*)&As[abase + i * 16 * 64 + sw0];
          af[i][1] = *(const half8*)&As[abase + i * 16 * 64 + sw1];
        }
      }
      if (qm == 0) {
        int bbase = (qn * 128 + wn * 32 + r16) * 64;
#pragma unroll
        for (int j = 0; j < 2; ++j) {
          bfr[qn][j][0] = *(const half8*)&Bs[bbase + j * 16 * 64 + sw0];
          bfr[qn][j][1] = *(const half8*)&Bs[bbase + j * 16 * 64 + sw1];
        }
      }
      // Stage one half-tile (issued after this phase's ds-reads). R1-exact.
      if (q == 0) stage_half(Bt, n0, t1, 1, &sB[nxt][8192], tid, K);
      else if (q == 1) stage_half(A, m0, t2, 0, &sA[cur][0], tid, K);
      else if (q == 2) stage_half(Bt, n0, t2, 0, &sB[cur][0], tid, K);
      else stage_half(A, m0, t2, 1, &sA[cur][8192], tid, K);
      __builtin_amdgcn_s_barrier();
      asm volatile("s_waitcnt lgkmcnt(0)" ::: "memory");
      __builtin_amdgcn_s_setprio(1);
#pragma unroll
      for (int i = 0; i < 4; ++i)
#pragma unroll
        for (int j = 0; j < 2; ++j) {
          acc[q][i * 2 + j] = __builtin_amdgcn_mfma_f32_16x16x32_f16(
              af[i][0], bfr[qn][j][0], acc[q][i * 2 + j], 0, 0, 0);
          acc[q][i * 2 + j] = __builtin_amdgcn_mfma_f32_16x16x32_f16(
              af[i][1], bfr[qn][j][1], acc[q][i * 2 + j], 0, 0, 0);
        }
      __builtin_amdgcn_s_setprio(0);
      if (q == 3) asm volatile("s_waitcnt vmcnt(6)" ::: "memory");
      __builtin_amdgcn_s_barrier();
    }
  }
  asm volatile("s_waitcnt vmcnt(0)" ::: "memory");  // drain clamped prefetch

  // Epilogue: bias + ReLU, f16 store.
  float bvv[2][2];
#pragma unroll
  for (int qn = 0; qn < 2; ++qn)
#pragma unroll
    for (int j = 0; j < 2; ++j)
      bvv[qn][j] = bias[n0 + qn * 128 + wn * 32 + j * 16 + r16];
#pragma unroll
  for (int q = 0; q < 4; ++q) {
    const int qm = q >> 1, qn = q & 1;
#pragma unroll
    for (int i = 0; i < 4; ++i)
#pragma unroll
      for (int j = 0; j < 2; ++j) {
#pragma unroll
        for (int r = 0; r < 4; ++r) {
          int m = m0 + qm * 128 + wm * 64 + i * 16 + quad * 4 + r;
          int n = n0 + qn * 128 + wn * 32 + j * 16 + r16;
          float v = acc[q][i * 2 + j][r] + bvv[qn][j];
          H[(size_t)m * N + n] = (_Float16)fmaxf(v, 0.f);
        }
      }
  }
}

// ---------------------------------------------------------------------------
// GEMM2 + fused SOFTMAX + fused COMPACT EMIT (R7): probs for a 64-row tile
// staged in LDS, then writes EMC[m][0..319]:
//   slots 0..199  = P[tg[l]]        (label probs)
//   slots 200..255 = 0
//   slots 256..319 = blank prob (64 REPLICATED copies — one per lane)
// Row = 1280 B (non-power-of-2 stride: no L2 set aliasing) vs R5's 2 KB.
// R6 lesson: a wave-UNIFORM blank load got scalarized (s_load); its only
// wait is lgkmcnt(0), which drains ALL prefetched scalar loads -> blank
// prefetch distance collapsed to ~1 row and ctc_dp doubled (60->147us).
// Replicating blank per-lane forces a coalesced VECTOR load (per-lane addr).
// ---------------------------------------------------------------------------
__global__ __launch_bounds__(256) void gemm_prob_kernel(
    const _Float16* __restrict__ A, const _Float16* __restrict__ Bt,
    const float* __restrict__ bias, const int* __restrict__ targets,
    float* __restrict__ EM, int M, int K) {
  constexpr int BK = 64;
  __shared__ __align__(16) _Float16 sA[64 * BK];   // 8 KB
  __shared__ __align__(16) _Float16 sB[VC_ * BK];  // 10 KB
  __shared__ float sP[64][VC_];                    // 20 KB prob tile
  int tid = threadIdx.x;
  int wave = tid >> 6, lane = tid & 63;
  int quad = lane >> 4, r16 = lane & 15;
  int m0 = blockIdx.x * 64;

  f32x4 acc[5];
#pragma unroll
  for (int j = 0; j < 5; ++j) acc[j] = {0.f, 0.f, 0.f, 0.f};

  for (int kt = 0; kt < K; kt += BK) {
#pragma unroll
    for (int jj = 0; jj < 2; ++jj) {
      int seg = tid + 256 * jj;  // 512 segs
      int row = seg >> 3, slot = seg & 7;
      int cg = slot ^ (row & 7);
      async16(A + (size_t)(m0 + row) * K + kt + cg * 8, &sA[seg * 8]);
    }
#pragma unroll
    for (int jj = 0; jj < 3; ++jj) {
      int seg = tid + 256 * jj;
      if (seg < VC_ * 8) {  // 640 segs; whole-wave masking
        int row = seg >> 3, slot = seg & 7;
        int cg = slot ^ (row & 7);
        async16(Bt + (size_t)row * K + kt + cg * 8, &sB[seg * 8]);
      }
    }
    __syncthreads();
#pragma unroll
    for (int ku = 0; ku < 2; ++ku) {
      int sw = ((ku * 4 + quad) ^ (r16 & 7)) * 8;
      half8 af = *(const half8*)&sA[(wave * 16 + r16) * BK + sw];
      half8 bfr[5];
#pragma unroll
      for (int j = 0; j < 5; ++j)
        bfr[j] = *(const half8*)&sB[(j * 16 + r16) * BK + sw];
#pragma unroll
      for (int j = 0; j < 5; ++j)
        acc[j] = __builtin_amdgcn_mfma_f32_16x16x32_f16(af, bfr[j], acc[j], 0, 0, 0);
    }
    __syncthreads();
  }
  float bv[5];
#pragma unroll
  for (int j = 0; j < 5; ++j) bv[j] = bias[j * 16 + r16];
#pragma unroll
  for (int rr = 0; rr < 4; ++rr) {
    float vals[5];
    float mx = -3.4e38f;
#pragma unroll
    for (int j = 0; j < 5; ++j) {
      vals[j] = acc[j][rr] + bv[j];
      mx = fmaxf(mx, vals[j]);
    }
#pragma unroll
    for (int d = 1; d < 16; d <<= 1) mx = fmaxf(mx, __shfl_xor(mx, d));
    float ex[5], sm = 0.f;
#pragma unroll
    for (int j = 0; j < 5; ++j) { ex[j] = __expf(vals[j] - mx); sm += ex[j]; }
#pragma unroll
    for (int d = 1; d < 16; d <<= 1) sm += __shfl_xor(sm, d);
    float rinv = 1.f / sm;
    int ml = wave * 16 + quad * 4 + rr;
#pragma unroll
    for (int j = 0; j < 5; ++j) sP[ml][j * 16 + r16] = ex[j] * rinv;
  }
  __syncthreads();

  // Compact emit: 64 rows x 320 slots; 4 threads per row, 80 slots each
  // (contiguous 320 B float4 stores). Region boundaries (200, 256) are
  // float4-aligned, so each float4 component picks its region cleanly.
  {
    int row = tid >> 2, q4 = tid & 3;
    int m = m0 + row;
    int b = m / TT_;
    const int* tg = targets + b * LMAX_;
    const float* pr = sP[row];
    float pb = pr[BLANK_];
    float* o = EM + (size_t)m * EMW + q4 * 80;
#pragma unroll 4
    for (int sc = 0; sc < 80; sc += 4) {
      int l = q4 * 80 + sc;
      float4 vv;
      vv.x = (l + 0 < LMAX_) ? pr[tg[l + 0]] : ((l + 0 >= 256) ? pb : 0.f);
      vv.y = (l + 1 < LMAX_) ? pr[tg[l + 1]] : ((l + 1 >= 256) ? pb : 0.f);
      vv.z = (l + 2 < LMAX_) ? pr[tg[l + 2]] : ((l + 2 >= 256) ? pb : 0.f);
      vv.w = (l + 3 < LMAX_) ? pr[tg[l + 3]] : ((l + 3 >= 256) ? pb : 0.f);
      *(float4*)o = vv;
      o += 4;
    }
  }
}

// ---------------------------------------------------------------------------
// CTC DP, forward/backward split. Linear domain, PER-LANE block-float scale.
// R7: compact EMC rows — lane reads f32x4 @ lane*4 (labels 4L..4L+3) and
// blank @ 256+lane (per-lane replicated copy -> VECTOR load, 8-deep
// prefetch preserved).  e0={bl,lv.x,bl,lv.y}, e1={bl,lv.z,bl,lv.w}
// reproduces the old per-state emissions exactly (R6 passed absmax 0).
// ---------------------------------------------------------------------------
__device__ __forceinline__ void dp_step_fwd(float (&bta)[8], int& k,
                                            const f32x4 e0, const f32x4 e1,
                                            const float (&am)[4], int lane) {
  float pm1 = __shfl_up(bta[7], 1);   // alpha[s0-1] (prev lane r=7)
  int pk = __shfl_up(k, 1);
  if (lane == 0) { pm1 = 0.f; pk = k; }
  int knew = max(k, pk);
  pm1 = ldexpf(pm1, pk - knew);
  int ds = k - knew;
#pragma unroll
  for (int r = 0; r < 8; ++r) bta[r] = ldexpf(bta[r], ds);
  k = knew;
  float nb[8];
  nb[0] = (bta[0] + pm1) * e0.x;
  nb[1] = fmaf(am[0], pm1, bta[1] + bta[0]) * e0.y;
  nb[2] = (bta[2] + bta[1]) * e0.z;
  nb[3] = fmaf(am[1], bta[1], bta[3] + bta[2]) * e0.w;
  nb[4] = (bta[4] + bta[3]) * e1.x;
  nb[5] = fmaf(am[2], bta[3], bta[5] + bta[4]) * e1.y;
  nb[6] = (bta[6] + bta[5]) * e1.z;
  nb[7] = fmaf(am[3], bta[5], bta[7] + bta[6]) * e1.w;
#pragma unroll
  for (int r = 0; r < 8; ++r) bta[r] = nb[r];
}

__device__ __forceinline__ void dp_step_bwd(float (&g)[8], int& k,
                                            const f32x4 e0, const f32x4 e1,
                                            const float (&amB)[4], int lane) {
  float gh[8];
  gh[0] = g[0] * e0.x; gh[1] = g[1] * e0.y;
  gh[2] = g[2] * e0.z; gh[3] = g[3] * e0.w;
  gh[4] = g[4] * e1.x; gh[5] = g[5] * e1.y;
  gh[6] = g[6] * e1.z; gh[7] = g[7] * e1.w;
  float qm1 = __shfl_down(gh[0], 1);
  float qm2 = __shfl_down(gh[1], 1);
  int nk = __shfl_down(k, 1);
  if (lane == 63) { qm1 = 0.f; qm2 = 0.f; nk = k; }
  int knew = max(k, nk);
  int dq = nk - knew;
  qm1 = ldexpf(qm1, dq);
  qm2 = ldexpf(qm2, dq);
  int ds = k - knew;
#pragma unroll
  for (int r = 0; r < 8; ++r) gh[r] = ldexpf(gh[r], ds);
  k = knew;
  g[0] = gh[0] + gh[1];
  g[1] = fmaf(amB[0], gh[3], gh[1] + gh[2]);
  g[2] = gh[2] + gh[3];
  g[3] = fmaf(amB[1], gh[5], gh[3] + gh[4]);
  g[4] = gh[4] + gh[5];
  g[5] = fmaf(amB[2], gh[7], gh[5] + gh[6]);
  g[6] = gh[6] + gh[7];
  g[7] = fmaf(amB[3], qm2, gh[7] + qm1);
}

__device__ __forceinline__ void dp_rescale(float (&v)[8], int& k) {
  float m = fmaxf(fmaxf(fmaxf(v[0], v[1]), fmaxf(v[2], v[3])),
                  fmaxf(fmaxf(v[4], v[5]), fmaxf(v[6], v[7])));
  int ex = (__float_as_int(m) >> 23) - 126;  // m>=0; m==0 -> harmless drift
  k += ex;
#pragma unroll
  for (int r = 0; r < 8; ++r) v[r] = ldexpf(v[r], -ex);
}

__device__ __forceinline__ float allow_f(const int* __restrict__ tg, int s) {
  if (!(s & 1) || s < 3) return 0.f;
  int li = s >> 1;
  if (li >= LMAX_) return 0.f;
  int lab = tg[li];
  return (lab != BLANK_ && lab != tg[li - 1]) ? 1.f : 0.f;
}

__global__ __launch_bounds__(128) void ctc_dp_kernel(
    const float* __restrict__ EM, const int* __restrict__ targets,
    const int* __restrict__ dlen, const int* __restrict__ tlen,
    float* __restrict__ out) {
  __shared__ float sg[SPAD];
  __shared__ int skg[64];
  int b = blockIdx.x;
  int wave = threadIdx.x >> 6;
  int lane = threadIdx.x & 63;
  const float* em4 = EM + (size_t)b * TT_ * EMW + lane * 4;    // labels 4L..4L+3
  const float* embl = EM + (size_t)b * TT_ * EMW + 256 + lane; // per-lane blank copy
  const int* tg = targets + b * LMAX_;
  int Tl = dlen[b], Ll = tlen[b];
  int tm = Tl >> 1;

  constexpr int PD = 8;
  f32x4 pf[PD];
  float pb[PD];
  float v[8];
  int k = 0;

  if (wave == 0) {
    float am[4];
#pragma unroll
    for (int j = 0; j < 4; ++j) am[j] = allow_f(tg, lane * 8 + 2 * j + 1);
    f32x4 lv0 = *(const f32x4*)(em4);
    float bl0 = embl[0];
#pragma unroll
    for (int r = 0; r < 8; ++r) v[r] = 0.f;
    if (lane == 0) { v[0] = bl0; v[1] = lv0.x; }
#pragma unroll
    for (int j = 0; j < PD; ++j) {
      int ri = min(1 + j, TT_ - 1);
      pf[j] = *(const f32x4*)(em4 + (size_t)ri * EMW);
      pb[j] = embl[(size_t)ri * EMW];
    }
    int t = 1;
    for (; t + (PD - 1) <= tm; t += PD) {
#pragma unroll
      for (int u = 0; u < PD; ++u) {
        f32x4 lv = pf[u]; float bl = pb[u];
        f32x4 e0 = {bl, lv.x, bl, lv.y};
        f32x4 e1 = {bl, lv.z, bl, lv.w};
        dp_step_fwd(v, k, e0, e1, am, lane);
        if (u & 1) dp_rescale(v, k);
        int ri = min(t + u + PD, TT_ - 1);
        pf[u] = *(const f32x4*)(em4 + (size_t)ri * EMW);
        pb[u] = embl[(size_t)ri * EMW];
      }
    }
#pragma unroll
    for (int u = 0; u < PD; ++u) {
      if (t + u <= tm) {
        f32x4 lv = pf[u]; float bl = pb[u];
        f32x4 e0 = {bl, lv.x, bl, lv.y};
        f32x4 e1 = {bl, lv.z, bl, lv.w};
        dp_step_fwd(v, k, e0, e1, am, lane);
        if (u & 1) dp_rescale(v, k);
      }
    }
  } else {
    float amB[4];
#pragma unroll
    for (int j = 0; j < 4; ++j) amB[j] = allow_f(tg, lane * 8 + 2 * j + 3);
    int s1 = 2 * Ll - 1, s2 = 2 * Ll;
#pragma unroll
    for (int r = 0; r < 8; ++r) {
      int s = lane * 8 + r;
      v[r] = (s == s1 || s == s2) ? 1.f : 0.f;
    }
#pragma unroll
    for (int j = 0; j < PD; ++j) {
      int ri = max(Tl - 1 - j, 0);
      pf[j] = *(const f32x4*)(em4 + (size_t)ri * EMW);
      pb[j] = embl[(size_t)ri * EMW];
    }
    int t = Tl - 1;
    for (; t - (PD - 1) > tm; t -= PD) {
#pragma unroll
      for (int u = 0; u < PD; ++u) {
        f32x4 lv = pf[u]; float bl = pb[u];
        f32x4 e0 = {bl, lv.x, bl, lv.y};
        f32x4 e1 = {bl, lv.z, bl, lv.w};
        dp_step_bwd(v, k, e0, e1, amB, lane);
        if (u & 1) dp_rescale(v, k);
        int ri = max(t - u - PD, 0);
        pf[u] = *(const f32x4*)(em4 + (size_t)ri * EMW);
        pb[u] = embl[(size_t)ri * EMW];
      }
    }
#pragma unroll
    for (int u = 0; u < PD; ++u) {
      if (t - u > tm) {
        f32x4 lv = pf[u]; float bl = pb[u];
        f32x4 e0 = {bl, lv.x, bl, lv.y};
        f32x4 e1 = {bl, lv.z, bl, lv.w};
        dp_step_bwd(v, k, e0, e1, amB, lane);
        if (u & 1) dp_rescale(v, k);
      }
    }
#pragma unroll
    for (int r = 0; r < 8; ++r) sg[lane * 8 + r] = v[r];
    skg[lane] = k;
  }
  __syncthreads();
  if (wave == 0) {
    float p = 0.f;
#pragma unroll
    for (int r = 0; r < 8; ++r) p = fmaf(v[r], sg[lane * 8 + r], p);
    int kk = k + skg[lane];
    if (p == 0.f) kk = -(1 << 30);
#pragma unroll
    for (int d = 1; d < 64; d <<= 1) {
      float po = __shfl_xor(p, d);
      int ko = __shfl_xor(kk, d);
      int km = max(kk, ko);
      p = ldexpf(p, kk - km) + ldexpf(po, ko - km);
      kk = km;
    }
    if (lane == 0) {
      float nll = 0.f;
      if (p > 0.f) nll = -((log2f(p) + (float)kk) * 0.69314718055994531f);
      atomicAdd(out, nll / (float)Tl * (1.f / BN_));
    }
  }
}

// ---------------------------------------------------------------------------
extern "C" void kernel_launch(void* const* d_in, const int* in_sizes, int n_in,
                              void* d_out, int out_size, void* d_ws, size_t ws_size,
                              hipStream_t stream) {
  const float* dec = (const float*)d_in[0];   // [B, D, T] f32
  const int* tgt   = (const int*)d_in[1];     // [B, LMAX]
  const int* dln   = (const int*)d_in[2];     // [B]
  const int* tln   = (const int*)d_in[3];     // [B]
  const float* W1  = (const float*)d_in[4];   // [D, D]
  const float* b1  = (const float*)d_in[5];   // [D]
  const float* W2  = (const float*)d_in[6];   // [D, V]
  const float* b2  = (const float*)d_in[7];   // [V]
  float* out = (float*)d_out;

  char* ws = (char*)d_ws;
  const size_t M = (size_t)BN_ * TT_;  // 32000
  _Float16* Af   = (_Float16*)(ws);                 // [M, D] f16
  float* EM      = (float*)(ws);                    // [B,T,EMW] f32 (aliases Af)
  _Float16* Hf   = (_Float16*)(ws + 65536000);      // [M, D] f16
  _Float16* W1T  = (_Float16*)(ws + 131072000);     // [D, D] f16 (W1^T)
  _Float16* W2T  = (_Float16*)(ws + 133169152);     // [V, D] f16 (W2^T)

  hipMemsetAsync(d_out, 0, sizeof(float), stream);

  transpose_all_kernel<<<dim3(16, 16, 34), 256, 0, stream>>>(
      dec, W1, W2, Af, W1T, W2T);
  gemm_relu_kernel<<<dim3((1024 / 256) * (M / 256), 1, 1), 512, 0, stream>>>(
      Af, W1T, b1, Hf, (int)M, DD_, DD_);
  gemm_prob_kernel<<<dim3(M / 64, 1, 1), 256, 0, stream>>>(
      Hf, W2T, b2, tgt, EM, (int)M, DD_);
  ctc_dp_kernel<<<dim3(BN_, 1, 1), 128, 0, stream>>>(EM, tgt, dln, tln, out);
}